// Round 1
// baseline (331.281 us; speedup 1.0000x reference)
//
#include <hip/hip_runtime.h>

namespace {
constexpr int kB = 16;
constexpr int kN = 131072;            // 2^17
constexpr int kNLog = 17;
constexpr int kCMid = 128;
constexpr int kCOut = 16;
constexpr int kCells32Log = 15;       // 32*32*32 = 2^15
constexpr int kCells64Log = 18;       // 64*64*64 = 2^18
constexpr int kCells32 = 1 << kCells32Log;
constexpr int kCells64 = 1 << kCells64Log;
constexpr long kOut32Elems = (long)kB * kCOut * kCells32;  // 8,388,608
}  // namespace

// ---------------------------------------------------------------------------
// Pass 1+2 fused: for each permuted position (b, i):
//   j = perm[b,i]; read x[b,j]; compute 32^3 and 64^3 cell indices;
//   atomicMax(winner, i+1); optionally compute MLP feat and store at [b,i].
// Cell index math uses __fmul_rn/__fadd_rn to forbid FMA contraction so the
// truncation boundaries match numpy's mul-then-add exactly.
// ---------------------------------------------------------------------------
template <bool STORE_FEAT>
__global__ __launch_bounds__(256) void fused_mlp_scatter(
    const float* __restrict__ x,
    const float* __restrict__ W1, const float* __restrict__ b1,
    const float* __restrict__ W2, const float* __restrict__ b2,
    const int* __restrict__ perm,
    unsigned int* __restrict__ win32, unsigned int* __restrict__ win64,
    float* __restrict__ feat)
{
    __shared__ float sW1[kCMid * 3];
    __shared__ float sb1[kCMid];
    __shared__ float sW2[kCOut * kCMid];
    __shared__ float sb2[kCOut];
    const int t = threadIdx.x;
    if (STORE_FEAT) {
        for (int idx = t; idx < kCMid * 3; idx += 256) sW1[idx] = W1[idx];
        for (int idx = t; idx < kCMid; idx += 256) sb1[idx] = b1[idx];
        for (int idx = t; idx < kCOut * kCMid; idx += 256) sW2[idx] = W2[idx];
        if (t < kCOut) sb2[t] = b2[t];
        __syncthreads();
    }

    const long gid = (long)blockIdx.x * 256 + t;  // over B*N permuted positions
    const int b = (int)(gid >> kNLog);
    const int i = (int)(gid & (kN - 1));
    const int j = perm[gid];

    const float* xp = x + ((long)b * kN + j) * 3;
    const float x0 = xp[0], x1 = xp[1], x2 = xp[2];

    // 32^3 cell
    const int ix32 = (int)fminf(fmaxf(__fadd_rn(__fmul_rn(x0, 32.0f), 16.5f), 0.0f), 31.0f);
    const int iy32 = (int)fminf(fmaxf(__fadd_rn(__fmul_rn(x1, 32.0f), 16.5f), 0.0f), 31.0f);
    const int iz32 = (int)fminf(fmaxf(__fadd_rn(__fmul_rn(x2, 32.0f), 16.5f), 0.0f), 31.0f);
    const int cell32 = (ix32 * 32 + iy32) * 32 + iz32;
    // 64^3 cell
    const int ix64 = (int)fminf(fmaxf(__fadd_rn(__fmul_rn(x0, 64.0f), 32.5f), 0.0f), 63.0f);
    const int iy64 = (int)fminf(fmaxf(__fadd_rn(__fmul_rn(x1, 64.0f), 32.5f), 0.0f), 63.0f);
    const int iz64 = (int)fminf(fmaxf(__fadd_rn(__fmul_rn(x2, 64.0f), 32.5f), 0.0f), 63.0f);
    const int cell64 = (ix64 * 64 + iy64) * 64 + iz64;

    const unsigned int pri = (unsigned int)(i + 1);
    atomicMax(&win32[b * kCells32 + cell32], pri);
    atomicMax(&win64[b * kCells64 + cell64], pri);

    if (STORE_FEAT) {
        float acc[kCOut];
        #pragma unroll
        for (int c = 0; c < kCOut; ++c) acc[c] = sb2[c];
        #pragma unroll 4
        for (int k = 0; k < kCMid; ++k) {
            float h = sW1[k * 3 + 0] * x0 + sW1[k * 3 + 1] * x1 + sW1[k * 3 + 2] * x2 + sb1[k];
            h = fmaxf(h, 0.0f);
            #pragma unroll
            for (int c = 0; c < kCOut; ++c) acc[c] += sW2[c * kCMid + k] * h;
        }
        float4* fp = (float4*)(feat + gid * kCOut);
        fp[0] = make_float4(acc[0], acc[1], acc[2], acc[3]);
        fp[1] = make_float4(acc[4], acc[5], acc[6], acc[7]);
        fp[2] = make_float4(acc[8], acc[9], acc[10], acc[11]);
        fp[3] = make_float4(acc[12], acc[13], acc[14], acc[15]);
    }
}

// ---------------------------------------------------------------------------
// Pass 3: one thread per output cell. Reads the winner; gathers (or
// recomputes) its 16 features; writes all 16 channels (zeros if empty) so
// the full output is rewritten deterministically each call.
// ---------------------------------------------------------------------------
template <int CLOG, bool RECOMPUTE>
__global__ __launch_bounds__(256) void gather_cells(
    const unsigned int* __restrict__ win,
    const float* __restrict__ feat,   // !RECOMPUTE
    const int* __restrict__ perm,     // RECOMPUTE
    const float* __restrict__ x,      // RECOMPUTE
    const float* __restrict__ W1, const float* __restrict__ b1,
    const float* __restrict__ W2, const float* __restrict__ b2,
    float* __restrict__ out)
{
    constexpr int cells = 1 << CLOG;
    __shared__ float sW1[kCMid * 3];
    __shared__ float sb1[kCMid];
    __shared__ float sW2[kCOut * kCMid];
    __shared__ float sb2[kCOut];
    const int t = threadIdx.x;
    if (RECOMPUTE) {
        for (int idx = t; idx < kCMid * 3; idx += 256) sW1[idx] = W1[idx];
        for (int idx = t; idx < kCMid; idx += 256) sb1[idx] = b1[idx];
        for (int idx = t; idx < kCOut * kCMid; idx += 256) sW2[idx] = W2[idx];
        if (t < kCOut) sb2[t] = b2[t];
        __syncthreads();
    }

    const long gid = (long)blockIdx.x * 256 + t;  // over B*cells
    const int b = (int)(gid >> CLOG);
    const int cell = (int)(gid & (cells - 1));
    const unsigned int w = win[gid];

    float v[kCOut];
    if (w == 0u) {
        #pragma unroll
        for (int c = 0; c < kCOut; ++c) v[c] = 0.0f;
    } else if (!RECOMPUTE) {
        const int i = (int)(w - 1u);
        const float4* fp = (const float4*)(feat + (((long)b << kNLog) + i) * kCOut);
        float4 f0 = fp[0], f1 = fp[1], f2 = fp[2], f3 = fp[3];
        v[0] = f0.x; v[1] = f0.y; v[2]  = f0.z; v[3]  = f0.w;
        v[4] = f1.x; v[5] = f1.y; v[6]  = f1.z; v[7]  = f1.w;
        v[8] = f2.x; v[9] = f2.y; v[10] = f2.z; v[11] = f2.w;
        v[12] = f3.x; v[13] = f3.y; v[14] = f3.z; v[15] = f3.w;
    } else {
        const int i = (int)(w - 1u);
        const int j = perm[((long)b << kNLog) + i];
        const float* xp = x + ((long)b * kN + j) * 3;
        const float x0 = xp[0], x1 = xp[1], x2 = xp[2];
        #pragma unroll
        for (int c = 0; c < kCOut; ++c) v[c] = sb2[c];
        #pragma unroll 4
        for (int k = 0; k < kCMid; ++k) {
            float h = sW1[k * 3 + 0] * x0 + sW1[k * 3 + 1] * x1 + sW1[k * 3 + 2] * x2 + sb1[k];
            h = fmaxf(h, 0.0f);
            #pragma unroll
            for (int c = 0; c < kCOut; ++c) v[c] += sW2[c * kCMid + k] * h;
        }
    }

    float* op = out + (((long)b * kCOut) << CLOG) + cell;
    #pragma unroll
    for (int c = 0; c < kCOut; ++c) op[(long)c << CLOG] = v[c];
}

extern "C" void kernel_launch(void* const* d_in, const int* in_sizes, int n_in,
                              void* d_out, int out_size, void* d_ws, size_t ws_size,
                              hipStream_t stream)
{
    const float* x  = (const float*)d_in[0];
    const float* W1 = (const float*)d_in[1];
    const float* b1 = (const float*)d_in[2];
    const float* W2 = (const float*)d_in[3];
    const float* b2 = (const float*)d_in[4];
    const int* perm = (const int*)d_in[5];

    float* out32 = (float*)d_out;
    float* out64 = out32 + kOut32Elems;

    unsigned int* win32 = (unsigned int*)d_ws;
    unsigned int* win64 = win32 + (size_t)kB * kCells32;
    const size_t winnerBytes = (size_t)kB * (kCells32 + kCells64) * sizeof(unsigned int);
    float* feat = (float*)((char*)d_ws + winnerBytes);
    const size_t featBytes = (size_t)kB * kN * kCOut * sizeof(float);
    const bool storeFeat = ws_size >= winnerBytes + featBytes;

    hipMemsetAsync(d_ws, 0, winnerBytes, stream);

    const int nPtsBlocks = (int)(((long)kB * kN) / 256);        // 8192
    const int n32Blocks  = (int)(((long)kB * kCells32) / 256);  // 2048
    const int n64Blocks  = (int)(((long)kB * kCells64) / 256);  // 16384
    dim3 blk(256);

    if (storeFeat) {
        fused_mlp_scatter<true><<<nPtsBlocks, blk, 0, stream>>>(
            x, W1, b1, W2, b2, perm, win32, win64, feat);
        gather_cells<kCells32Log, false><<<n32Blocks, blk, 0, stream>>>(
            win32, feat, perm, x, W1, b1, W2, b2, out32);
        gather_cells<kCells64Log, false><<<n64Blocks, blk, 0, stream>>>(
            win64, feat, perm, x, W1, b1, W2, b2, out64);
    } else {
        fused_mlp_scatter<false><<<nPtsBlocks, blk, 0, stream>>>(
            x, W1, b1, W2, b2, perm, win32, win64, nullptr);
        gather_cells<kCells32Log, true><<<n32Blocks, blk, 0, stream>>>(
            win32, feat, perm, x, W1, b1, W2, b2, out32);
        gather_cells<kCells64Log, true><<<n64Blocks, blk, 0, stream>>>(
            win64, feat, perm, x, W1, b1, W2, b2, out64);
    }
}

// Round 2
// 320.601 us; speedup vs baseline: 1.0333x; 1.0333x over previous
//
#include <hip/hip_runtime.h>

namespace {
constexpr int kB = 16;
constexpr int kN = 131072;            // 2^17
constexpr int kNLog = 17;
constexpr int kCMid = 128;
constexpr int kCOut = 16;
constexpr int kCells32Log = 15;       // 32^3
constexpr int kCells64Log = 18;       // 64^3
constexpr int kCells32 = 1 << kCells32Log;
constexpr int kCells64 = 1 << kCells64Log;
constexpr long kOut32Elems = (long)kB * kCOut * kCells32;
constexpr int kP = 4;                 // points per thread in fused kernel
}  // namespace

// ---------------------------------------------------------------------------
// Stage packed weights into ws: W1p[k][4] = (w0,w1,w2,b1k); W2t[k][16].
// Contiguous float4 rows -> wave-uniform s_load-able reads in the hot loop.
// ---------------------------------------------------------------------------
__global__ __launch_bounds__(256) void pack_weights(
    const float* __restrict__ W1, const float* __restrict__ b1,
    const float* __restrict__ W2,
    float* __restrict__ W1p, float* __restrict__ W2t)
{
    const int t = threadIdx.x;
    for (int k = t; k < kCMid; k += 256) {
        W1p[k * 4 + 0] = W1[k * 3 + 0];
        W1p[k * 4 + 1] = W1[k * 3 + 1];
        W1p[k * 4 + 2] = W1[k * 3 + 2];
        W1p[k * 4 + 3] = b1[k];
    }
    for (int idx = t; idx < kCOut * kCMid; idx += 256) {
        const int c = idx >> 7;        // idx / 128
        const int k = idx & 127;
        W2t[k * kCOut + c] = W2[idx];
    }
}

// ---------------------------------------------------------------------------
// Fused: per permuted position (b,i): gather x, scatter atomicMax winners,
// compute MLP (weights via uniform global reads, amortized over kP points),
// store feat[b,i,0:16].
// Cell math uses __fmul_rn/__fadd_rn (no FMA contraction) to match numpy
// truncation boundaries exactly.
// ---------------------------------------------------------------------------
__global__ __launch_bounds__(256) void fused_mlp_scatter(
    const float* __restrict__ x,
    const int* __restrict__ perm,
    const float* __restrict__ W1p, const float* __restrict__ W2t,
    const float* __restrict__ b2,
    unsigned int* __restrict__ win32, unsigned int* __restrict__ win64,
    float* __restrict__ feat)
{
    const int t = threadIdx.x;
    const long base = (long)blockIdx.x * (256 * kP);

    float x0[kP], x1[kP], x2[kP];

    #pragma unroll
    for (int p = 0; p < kP; ++p) {
        const long gid = base + p * 256 + t;
        const int b = (int)(gid >> kNLog);
        const int i = (int)(gid & (kN - 1));
        const int j = perm[gid];
        const float* xp = x + ((long)b * kN + j) * 3;
        const float v0 = xp[0], v1 = xp[1], v2 = xp[2];
        x0[p] = v0; x1[p] = v1; x2[p] = v2;

        const int ix32 = (int)fminf(fmaxf(__fadd_rn(__fmul_rn(v0, 32.0f), 16.5f), 0.0f), 31.0f);
        const int iy32 = (int)fminf(fmaxf(__fadd_rn(__fmul_rn(v1, 32.0f), 16.5f), 0.0f), 31.0f);
        const int iz32 = (int)fminf(fmaxf(__fadd_rn(__fmul_rn(v2, 32.0f), 16.5f), 0.0f), 31.0f);
        const int ix64 = (int)fminf(fmaxf(__fadd_rn(__fmul_rn(v0, 64.0f), 32.5f), 0.0f), 63.0f);
        const int iy64 = (int)fminf(fmaxf(__fadd_rn(__fmul_rn(v1, 64.0f), 32.5f), 0.0f), 63.0f);
        const int iz64 = (int)fminf(fmaxf(__fadd_rn(__fmul_rn(v2, 64.0f), 32.5f), 0.0f), 63.0f);
        const unsigned int pri = (unsigned int)(i + 1);
        atomicMax(&win32[b * kCells32 + (ix32 * 32 + iy32) * 32 + iz32], pri);
        atomicMax(&win64[b * kCells64 + (ix64 * 64 + iy64) * 64 + iz64], pri);
    }

    float acc[kP][kCOut];
    #pragma unroll
    for (int p = 0; p < kP; ++p)
        #pragma unroll
        for (int c = 0; c < kCOut; ++c) acc[p][c] = 0.0f;

    const float4* __restrict__ w1v = (const float4*)W1p;
    const float4* __restrict__ w2v = (const float4*)W2t;

    #pragma unroll 4
    for (int k = 0; k < kCMid; ++k) {
        const float4 w1 = w1v[k];                 // uniform address
        float h[kP];
        #pragma unroll
        for (int p = 0; p < kP; ++p)
            h[p] = fmaxf(fmaf(w1.x, x0[p], fmaf(w1.y, x1[p], fmaf(w1.z, x2[p], w1.w))), 0.0f);
        #pragma unroll
        for (int q = 0; q < 4; ++q) {
            const float4 w = w2v[k * 4 + q];      // uniform address
            #pragma unroll
            for (int p = 0; p < kP; ++p) {
                acc[p][4 * q + 0] = fmaf(w.x, h[p], acc[p][4 * q + 0]);
                acc[p][4 * q + 1] = fmaf(w.y, h[p], acc[p][4 * q + 1]);
                acc[p][4 * q + 2] = fmaf(w.z, h[p], acc[p][4 * q + 2]);
                acc[p][4 * q + 3] = fmaf(w.w, h[p], acc[p][4 * q + 3]);
            }
        }
    }

    const float4 bq0 = ((const float4*)b2)[0];
    const float4 bq1 = ((const float4*)b2)[1];
    const float4 bq2 = ((const float4*)b2)[2];
    const float4 bq3 = ((const float4*)b2)[3];

    #pragma unroll
    for (int p = 0; p < kP; ++p) {
        const long gid = base + p * 256 + t;
        float4* fp = (float4*)(feat + gid * kCOut);
        fp[0] = make_float4(acc[p][0]  + bq0.x, acc[p][1]  + bq0.y, acc[p][2]  + bq0.z, acc[p][3]  + bq0.w);
        fp[1] = make_float4(acc[p][4]  + bq1.x, acc[p][5]  + bq1.y, acc[p][6]  + bq1.z, acc[p][7]  + bq1.w);
        fp[2] = make_float4(acc[p][8]  + bq2.x, acc[p][9]  + bq2.y, acc[p][10] + bq2.z, acc[p][11] + bq2.w);
        fp[3] = make_float4(acc[p][12] + bq3.x, acc[p][13] + bq3.y, acc[p][14] + bq3.z, acc[p][15] + bq3.w);
    }
}

// ---------------------------------------------------------------------------
// Per-cell gather: read winner, fetch (or recompute) its 16 features, write
// all 16 channels (zeros if empty) so the full output is rewritten each call.
// ---------------------------------------------------------------------------
template <int CLOG, bool RECOMPUTE>
__global__ __launch_bounds__(256) void gather_cells(
    const unsigned int* __restrict__ win,
    const float* __restrict__ feat,
    const int* __restrict__ perm,
    const float* __restrict__ x,
    const float* __restrict__ W1p, const float* __restrict__ W2t,
    const float* __restrict__ b2,
    float* __restrict__ out)
{
    constexpr int cells = 1 << CLOG;
    const long gid = (long)blockIdx.x * 256 + threadIdx.x;  // over B*cells
    const int b = (int)(gid >> CLOG);
    const int cell = (int)(gid & (cells - 1));
    const unsigned int w = win[gid];

    float v[kCOut];
    if (w == 0u) {
        #pragma unroll
        for (int c = 0; c < kCOut; ++c) v[c] = 0.0f;
    } else if (!RECOMPUTE) {
        const int i = (int)(w - 1u);
        const float4* fp = (const float4*)(feat + (((long)b << kNLog) + i) * kCOut);
        const float4 f0 = fp[0], f1 = fp[1], f2 = fp[2], f3 = fp[3];
        v[0] = f0.x; v[1] = f0.y; v[2]  = f0.z; v[3]  = f0.w;
        v[4] = f1.x; v[5] = f1.y; v[6]  = f1.z; v[7]  = f1.w;
        v[8] = f2.x; v[9] = f2.y; v[10] = f2.z; v[11] = f2.w;
        v[12] = f3.x; v[13] = f3.y; v[14] = f3.z; v[15] = f3.w;
    } else {
        const int i = (int)(w - 1u);
        const int j = perm[((long)b << kNLog) + i];
        const float* xp = x + ((long)b * kN + j) * 3;
        const float v0 = xp[0], v1 = xp[1], v2 = xp[2];
        #pragma unroll
        for (int c = 0; c < kCOut; ++c) v[c] = 0.0f;
        #pragma unroll 4
        for (int k = 0; k < kCMid; ++k) {
            const float4 w1 = ((const float4*)W1p)[k];
            const float h = fmaxf(fmaf(w1.x, v0, fmaf(w1.y, v1, fmaf(w1.z, v2, w1.w))), 0.0f);
            #pragma unroll
            for (int q = 0; q < 4; ++q) {
                const float4 wq = ((const float4*)W2t)[k * 4 + q];
                v[4 * q + 0] = fmaf(wq.x, h, v[4 * q + 0]);
                v[4 * q + 1] = fmaf(wq.y, h, v[4 * q + 1]);
                v[4 * q + 2] = fmaf(wq.z, h, v[4 * q + 2]);
                v[4 * q + 3] = fmaf(wq.w, h, v[4 * q + 3]);
            }
        }
        #pragma unroll
        for (int c = 0; c < kCOut; ++c) v[c] += b2[c];
    }

    float* op = out + (((long)b * kCOut) << CLOG) + cell;
    #pragma unroll
    for (int c = 0; c < kCOut; ++c) op[(long)c << CLOG] = v[c];
}

extern "C" void kernel_launch(void* const* d_in, const int* in_sizes, int n_in,
                              void* d_out, int out_size, void* d_ws, size_t ws_size,
                              hipStream_t stream)
{
    const float* x  = (const float*)d_in[0];
    const float* W1 = (const float*)d_in[1];
    const float* b1 = (const float*)d_in[2];
    const float* W2 = (const float*)d_in[3];
    const float* b2 = (const float*)d_in[4];
    const int* perm = (const int*)d_in[5];

    float* out32 = (float*)d_out;
    float* out64 = out32 + kOut32Elems;

    // ws layout: [W1p 2KB][W2t 8KB][pad->16KB][win32][win64][feat]
    float* W1p = (float*)d_ws;
    float* W2t = W1p + kCMid * 4;
    unsigned int* win32 = (unsigned int*)((char*)d_ws + 16384);
    unsigned int* win64 = win32 + (size_t)kB * kCells32;
    const size_t winnerBytes = (size_t)kB * (kCells32 + kCells64) * sizeof(unsigned int);
    float* feat = (float*)((char*)win32 + winnerBytes);
    const size_t featBytes = (size_t)kB * kN * kCOut * sizeof(float);
    const bool storeFeat = ws_size >= 16384 + winnerBytes + featBytes;

    hipMemsetAsync(win32, 0, winnerBytes, stream);
    pack_weights<<<1, 256, 0, stream>>>(W1, b1, W2, W1p, W2t);

    const int nPtsBlocks = (int)(((long)kB * kN) / (256 * kP));  // 2048
    const int n32Blocks  = (int)(((long)kB * kCells32) / 256);   // 2048
    const int n64Blocks  = (int)(((long)kB * kCells64) / 256);   // 16384
    dim3 blk(256);

    fused_mlp_scatter<<<nPtsBlocks, blk, 0, stream>>>(
        x, perm, W1p, W2t, b2, win32, win64, feat);

    if (storeFeat) {
        gather_cells<kCells32Log, false><<<n32Blocks, blk, 0, stream>>>(
            win32, feat, perm, x, W1p, W2t, b2, out32);
        gather_cells<kCells64Log, false><<<n64Blocks, blk, 0, stream>>>(
            win64, feat, perm, x, W1p, W2t, b2, out64);
    } else {
        gather_cells<kCells32Log, true><<<n32Blocks, blk, 0, stream>>>(
            win32, feat, perm, x, W1p, W2t, b2, out32);
        gather_cells<kCells64Log, true><<<n64Blocks, blk, 0, stream>>>(
            win64, feat, perm, x, W1p, W2t, b2, out64);
    }
}